// Round 1
// baseline (1258.877 us; speedup 1.0000x reference)
//
#include <hip/hip_runtime.h>
#include <hip/hip_bf16.h>

#define N_NODES 100000
#define N_EDGES 3200000
#define F_IN 128
#define HID 16
#define N_CLASSES 32
#define N_RELS 20
#define BN_EPS 1e-5f

// ---------------- workspace layout (bytes) ----------------
#define OFF_CNT   0ull                  // int[N_RELS*N_NODES]  8,000,000 B
#define OFF_AGG1  8000000ull            // float[N*16]          6,400,000 B
#define OFF_OUT1  14400000ull           // float[N*16]
#define OFF_HBN   20800000ull           // float[N*16]
#define OFF_BUF2  27200000ull           // float[N*32]         12,800,000 B
#define OFF_ST1   40000000ull           // float[32]
#define OFF_ST2   40000256ull           // float[64]
#define OFF_H1    40000512ull           // bf16[R*N*16]        64,000,000 B
#define NEED_FAST (OFF_H1 + 64000000ull)

// ---------------- kernels ----------------

__global__ void count_kernel(const int* __restrict__ et, const int* __restrict__ dst,
                             int* __restrict__ cnt) {
    int e = blockIdx.x * 256 + threadIdx.x;
    if (e < N_EDGES) {
        atomicAdd(&cnt[et[e] * N_NODES + dst[e]], 1);
    }
}

// h1[r,n,j] = sum_f x[n,f] * W1[r,f,j]   (bf16 output)
__global__ void transform1(const float* __restrict__ x, const float* __restrict__ W1,
                           __hip_bfloat16* __restrict__ h1) {
    __shared__ float w[F_IN * HID];  // 8KB, one relation
    int r = blockIdx.y;
    const float* Wr = W1 + r * (F_IN * HID);
    for (int i = threadIdx.x; i < F_IN * HID; i += 256) w[i] = Wr[i];
    __syncthreads();
    int grp = threadIdx.x >> 4, lane = threadIdx.x & 15;
    int base = blockIdx.x * 64;
    for (int it = 0; it < 4; ++it) {
        int n = base + it * 16 + grp;
        if (n < N_NODES) {
            const float4* xp = (const float4*)(x + (size_t)n * F_IN);
            float acc = 0.f;
#pragma unroll
            for (int f4 = 0; f4 < F_IN / 4; ++f4) {
                float4 xv = xp[f4];
                acc = fmaf(xv.x, w[(4 * f4 + 0) * HID + lane], acc);
                acc = fmaf(xv.y, w[(4 * f4 + 1) * HID + lane], acc);
                acc = fmaf(xv.z, w[(4 * f4 + 2) * HID + lane], acc);
                acc = fmaf(xv.w, w[(4 * f4 + 3) * HID + lane], acc);
            }
            h1[((size_t)r * N_NODES + n) * HID + lane] = __float2bfloat16(acc);
        }
    }
}

// fast path: gather precomputed h1, scale by 1/cnt, scatter-add
// template arg encodes ws_size bucket (1: >=NEED_FAST, 2: >=256MB, 3: >=512MB) for profiling info
template <int WS_BUCKET>
__global__ void conv1_gather(const __hip_bfloat16* __restrict__ h1,
                             const int* __restrict__ src, const int* __restrict__ dst,
                             const int* __restrict__ et, const int* __restrict__ cnt,
                             float* __restrict__ agg1) {
    int g = (blockIdx.x * 256 + threadIdx.x) >> 4;  // edge id
    int lane = threadIdx.x & 15;
    if (g < N_EDGES) {
        int r = et[g], s = src[g], d = dst[g];
        float norm = 1.0f / (float)cnt[r * N_NODES + d];
        float v = __bfloat162float(h1[((size_t)(r * N_NODES + s)) * HID + lane]);
        atomicAdd(&agg1[d * HID + lane], v * norm);
    }
}

// slow fallback (small ws): per-edge on-the-fly transform
__global__ void conv1_direct(const float* __restrict__ x, const float* __restrict__ W1,
                             const int* __restrict__ src, const int* __restrict__ dst,
                             const int* __restrict__ et, const int* __restrict__ cnt,
                             float* __restrict__ agg1) {
    int g = (blockIdx.x * 256 + threadIdx.x) >> 4;
    int lane = threadIdx.x & 15;
    if (g < N_EDGES) {
        int r = et[g], s = src[g], d = dst[g];
        float norm = 1.0f / (float)cnt[r * N_NODES + d];
        const float4* xp = (const float4*)(x + (size_t)s * F_IN);
        const float* wb = W1 + r * (F_IN * HID) + lane;
        float acc = 0.f;
#pragma unroll
        for (int f4 = 0; f4 < F_IN / 4; ++f4) {
            float4 xv = xp[f4];
            acc = fmaf(xv.x, wb[(4 * f4 + 0) * HID], acc);
            acc = fmaf(xv.y, wb[(4 * f4 + 1) * HID], acc);
            acc = fmaf(xv.z, wb[(4 * f4 + 2) * HID], acc);
            acc = fmaf(xv.w, wb[(4 * f4 + 3) * HID], acc);
        }
        atomicAdd(&agg1[d * HID + lane], acc * norm);
    }
}

// out1[n,j] = agg1[n,j] + sum_f x[n,f]*root1[f,j] + b1[j]
__global__ void root1_kernel(const float* __restrict__ x, const float* __restrict__ root1,
                             const float* __restrict__ b1, const float* __restrict__ agg1,
                             float* __restrict__ out1) {
    __shared__ float w[F_IN * HID];
    for (int i = threadIdx.x; i < F_IN * HID; i += 256) w[i] = root1[i];
    __syncthreads();
    int grp = threadIdx.x >> 4, lane = threadIdx.x & 15;
    int base = blockIdx.x * 64;
    for (int it = 0; it < 4; ++it) {
        int n = base + it * 16 + grp;
        if (n < N_NODES) {
            const float4* xp = (const float4*)(x + (size_t)n * F_IN);
            float acc = 0.f;
#pragma unroll
            for (int f4 = 0; f4 < F_IN / 4; ++f4) {
                float4 xv = xp[f4];
                acc = fmaf(xv.x, w[(4 * f4 + 0) * HID + lane], acc);
                acc = fmaf(xv.y, w[(4 * f4 + 1) * HID + lane], acc);
                acc = fmaf(xv.z, w[(4 * f4 + 2) * HID + lane], acc);
                acc = fmaf(xv.w, w[(4 * f4 + 3) * HID + lane], acc);
            }
            out1[(size_t)n * HID + lane] = agg1[(size_t)n * HID + lane] + acc + b1[lane];
        }
    }
}

template <int CH>
__global__ void bn_stats(const float* __restrict__ v, float* __restrict__ stats) {
    __shared__ float ls[CH], lq[CH];
    if (threadIdx.x < CH) { ls[threadIdx.x] = 0.f; lq[threadIdx.x] = 0.f; }
    __syncthreads();
    const int total = N_NODES * CH;
    int j = threadIdx.x % CH;
    float s = 0.f, q = 0.f;
    for (int i = blockIdx.x * blockDim.x + threadIdx.x; i < total; i += gridDim.x * blockDim.x) {
        float t = v[i];
        s += t; q += t * t;
    }
    atomicAdd(&ls[j], s);
    atomicAdd(&lq[j], q);
    __syncthreads();
    if (threadIdx.x < CH) {
        atomicAdd(&stats[threadIdx.x], ls[threadIdx.x]);
        atomicAdd(&stats[CH + threadIdx.x], lq[threadIdx.x]);
    }
}

__global__ void bn_relu1(const float* __restrict__ out1, const float* __restrict__ stats,
                         const float* __restrict__ gamma, const float* __restrict__ beta,
                         float* __restrict__ hbn) {
    int i = blockIdx.x * 256 + threadIdx.x;
    if (i < N_NODES * HID) {
        int j = i & (HID - 1);
        float mean = stats[j] * (1.0f / N_NODES);
        float var = stats[HID + j] * (1.0f / N_NODES) - mean * mean;
        float rs = rsqrtf(var + BN_EPS);
        float val = (out1[i] - mean) * rs * gamma[j] + beta[j];
        hbn[i] = fmaxf(val, 0.f);
    }
}

__global__ void conv2_edge(const float* __restrict__ hbn, const float* __restrict__ W2,
                           const int* __restrict__ src, const int* __restrict__ dst,
                           const int* __restrict__ et, const int* __restrict__ cnt,
                           float* __restrict__ agg2) {
    __shared__ float w[N_RELS * HID * N_CLASSES];  // 40KB
    for (int i = threadIdx.x; i < N_RELS * HID * N_CLASSES; i += 256) w[i] = W2[i];
    __syncthreads();
    int grp = threadIdx.x >> 5, lane = threadIdx.x & 31;
    int base = blockIdx.x * 256;
    for (int it = 0; it < 32; ++it) {
        int e = base + it * 8 + grp;
        if (e < N_EDGES) {
            int r = et[e], s = src[e], d = dst[e];
            float norm = 1.0f / (float)cnt[r * N_NODES + d];
            const float4* hp = (const float4*)(hbn + (size_t)s * HID);
            const float* wr = w + r * (HID * N_CLASSES) + lane;
            float4 a0 = hp[0], a1 = hp[1], a2 = hp[2], a3 = hp[3];
            float acc = 0.f;
            acc = fmaf(a0.x, wr[0 * 32], acc);  acc = fmaf(a0.y, wr[1 * 32], acc);
            acc = fmaf(a0.z, wr[2 * 32], acc);  acc = fmaf(a0.w, wr[3 * 32], acc);
            acc = fmaf(a1.x, wr[4 * 32], acc);  acc = fmaf(a1.y, wr[5 * 32], acc);
            acc = fmaf(a1.z, wr[6 * 32], acc);  acc = fmaf(a1.w, wr[7 * 32], acc);
            acc = fmaf(a2.x, wr[8 * 32], acc);  acc = fmaf(a2.y, wr[9 * 32], acc);
            acc = fmaf(a2.z, wr[10 * 32], acc); acc = fmaf(a2.w, wr[11 * 32], acc);
            acc = fmaf(a3.x, wr[12 * 32], acc); acc = fmaf(a3.y, wr[13 * 32], acc);
            acc = fmaf(a3.z, wr[14 * 32], acc); acc = fmaf(a3.w, wr[15 * 32], acc);
            atomicAdd(&agg2[(size_t)d * N_CLASSES + lane], acc * norm);
        }
    }
}

// buf2[n,c] += sum_k hbn[n,k]*root2[k,c] + b2[c]   (in-place on agg2)
__global__ void root2_kernel(const float* __restrict__ hbn, const float* __restrict__ root2,
                             const float* __restrict__ b2, float* __restrict__ buf2) {
    __shared__ float w[HID * N_CLASSES];
    for (int i = threadIdx.x; i < HID * N_CLASSES; i += 256) w[i] = root2[i];
    __syncthreads();
    int grp = threadIdx.x >> 5, lane = threadIdx.x & 31;
    int n = blockIdx.x * 8 + grp;
    if (n < N_NODES) {
        const float4* hp = (const float4*)(hbn + (size_t)n * HID);
        float4 a0 = hp[0], a1 = hp[1], a2 = hp[2], a3 = hp[3];
        float acc = 0.f;
        acc = fmaf(a0.x, w[0 * 32 + lane], acc);  acc = fmaf(a0.y, w[1 * 32 + lane], acc);
        acc = fmaf(a0.z, w[2 * 32 + lane], acc);  acc = fmaf(a0.w, w[3 * 32 + lane], acc);
        acc = fmaf(a1.x, w[4 * 32 + lane], acc);  acc = fmaf(a1.y, w[5 * 32 + lane], acc);
        acc = fmaf(a1.z, w[6 * 32 + lane], acc);  acc = fmaf(a1.w, w[7 * 32 + lane], acc);
        acc = fmaf(a2.x, w[8 * 32 + lane], acc);  acc = fmaf(a2.y, w[9 * 32 + lane], acc);
        acc = fmaf(a2.z, w[10 * 32 + lane], acc); acc = fmaf(a2.w, w[11 * 32 + lane], acc);
        acc = fmaf(a3.x, w[12 * 32 + lane], acc); acc = fmaf(a3.y, w[13 * 32 + lane], acc);
        acc = fmaf(a3.z, w[14 * 32 + lane], acc); acc = fmaf(a3.w, w[15 * 32 + lane], acc);
        size_t o = (size_t)n * N_CLASSES + lane;
        buf2[o] = buf2[o] + acc + b2[lane];
    }
}

__global__ void final_kernel(const float* __restrict__ buf2, const float* __restrict__ stats,
                             const float* __restrict__ gamma, const float* __restrict__ beta,
                             float* __restrict__ out) {
    int idx = blockIdx.x * 256 + threadIdx.x;  // over N*32, exact
    int j = threadIdx.x & 31;
    float mean = stats[j] * (1.0f / N_NODES);
    float var = stats[N_CLASSES + j] * (1.0f / N_NODES) - mean * mean;
    float rs = rsqrtf(var + BN_EPS);
    float v = fmaxf((buf2[idx] - mean) * rs * gamma[j] + beta[j], 0.f);
    float m = v;
#pragma unroll
    for (int o = 16; o >= 1; o >>= 1) m = fmaxf(m, __shfl_xor(m, o, 32));
    float ex = __expf(v - m);
    float ssum = ex;
#pragma unroll
    for (int o = 16; o >= 1; o >>= 1) ssum += __shfl_xor(ssum, o, 32);
    out[idx] = (v - m) - logf(ssum);
}

// ---------------- launcher ----------------
extern "C" void kernel_launch(void* const* d_in, const int* in_sizes, int n_in,
                              void* d_out, int out_size, void* d_ws, size_t ws_size,
                              hipStream_t stream) {
    const float* x      = (const float*)d_in[0];
    const int*   eidx   = (const int*)d_in[1];
    const int*   etype  = (const int*)d_in[2];
    const float* W1     = (const float*)d_in[3];
    const float* root1  = (const float*)d_in[4];
    const float* b1     = (const float*)d_in[5];
    const float* gamma1 = (const float*)d_in[6];
    const float* beta1  = (const float*)d_in[7];
    const float* W2     = (const float*)d_in[8];
    const float* root2  = (const float*)d_in[9];
    const float* b2     = (const float*)d_in[10];
    const float* gamma2 = (const float*)d_in[11];
    const float* beta2  = (const float*)d_in[12];

    const int* src = eidx;
    const int* dst = eidx + N_EDGES;

    char* ws = (char*)d_ws;
    int*   cnt   = (int*)(ws + OFF_CNT);
    float* agg1  = (float*)(ws + OFF_AGG1);
    float* out1  = (float*)(ws + OFF_OUT1);
    float* hbn   = (float*)(ws + OFF_HBN);
    float* buf2  = (float*)(ws + OFF_BUF2);
    float* st1   = (float*)(ws + OFF_ST1);
    float* st2   = (float*)(ws + OFF_ST2);
    __hip_bfloat16* h1 = (__hip_bfloat16*)(ws + OFF_H1);

    float* out = (float*)d_out;

    hipMemsetAsync(cnt, 0, 8000000ull, stream);
    hipMemsetAsync(agg1, 0, 6400000ull, stream);
    hipMemsetAsync(buf2, 0, 12800000ull, stream);
    hipMemsetAsync(st1, 0, 256, stream);
    hipMemsetAsync(st2, 0, 256, stream);

    count_kernel<<<(N_EDGES + 255) / 256, 256, 0, stream>>>(etype, dst, cnt);

    const int edge16_blocks = (N_EDGES * 16 + 255) / 256;  // 200000
    if (ws_size >= NEED_FAST) {
        transform1<<<dim3((N_NODES + 63) / 64, N_RELS), 256, 0, stream>>>(x, W1, h1);
        if (ws_size >= (512ull << 20))
            conv1_gather<3><<<edge16_blocks, 256, 0, stream>>>(h1, src, dst, etype, cnt, agg1);
        else if (ws_size >= (256ull << 20))
            conv1_gather<2><<<edge16_blocks, 256, 0, stream>>>(h1, src, dst, etype, cnt, agg1);
        else
            conv1_gather<1><<<edge16_blocks, 256, 0, stream>>>(h1, src, dst, etype, cnt, agg1);
    } else {
        conv1_direct<<<edge16_blocks, 256, 0, stream>>>(x, W1, src, dst, etype, cnt, agg1);
    }

    root1_kernel<<<(N_NODES + 63) / 64, 256, 0, stream>>>(x, root1, b1, agg1, out1);
    bn_stats<HID><<<512, 256, 0, stream>>>(out1, st1);
    bn_relu1<<<(N_NODES * HID + 255) / 256, 256, 0, stream>>>(out1, st1, gamma1, beta1, hbn);

    conv2_edge<<<(N_EDGES + 255) / 256, 256, 0, stream>>>(hbn, W2, src, dst, etype, cnt, buf2);
    root2_kernel<<<(N_NODES + 7) / 8, 256, 0, stream>>>(hbn, root2, b2, buf2);
    bn_stats<N_CLASSES><<<512, 256, 0, stream>>>(buf2, st2);
    final_kernel<<<(N_NODES * N_CLASSES + 255) / 256, 256, 0, stream>>>(buf2, st2, gamma2, beta2, out);
}

// Round 2
// 868.636 us; speedup vs baseline: 1.4493x; 1.4493x over previous
//
#include <hip/hip_runtime.h>
#include <hip/hip_bf16.h>

#define N_NODES 100000
#define N_EDGES 3200000
#define F_IN 128
#define HID 16
#define N_CLASSES 32
#define N_RELS 20
#define BN_EPS 1e-5f

// ---------------- workspace layout (bytes) ----------------
#define OFF_CNT   0ull                   // int[N_RELS*N_NODES]   8,000,000
#define OFF_AGG1  8000000ull             // float[N*16]           6,400,000 (reused as out1 and hbn, in place)
#define OFF_BUF2  14400000ull            // float[N*32]          12,800,000
#define OFF_ST1   27200000ull            // float[32]                   256
#define OFF_ST2   27200256ull            // float[64]                   256
#define OFF_WT    27200512ull            // bf16[21*16*128]          86,016
#define OFF_H1    27286528ull            // bf16[21*N*16]        67,200,000  -> end 94,486,528

typedef __attribute__((ext_vector_type(8))) short bf16x8;
typedef __attribute__((ext_vector_type(4))) float f32x4;

__device__ inline short f2bf(float f) {
    __hip_bfloat16 h = __float2bfloat16(f);
    union { __hip_bfloat16 h; short s; } u; u.h = h;
    return u.s;
}

// ---------------- kernels ----------------

__global__ void count_kernel(const int* __restrict__ et, const int* __restrict__ dst,
                             int* __restrict__ cnt) {
    int e = blockIdx.x * 256 + threadIdx.x;
    if (e < N_EDGES) {
        atomicAdd(&cnt[et[e] * N_NODES + dst[e]], 1);
    }
}

// Wt[r][o][f] = W1[r][f][o] (r<20), root1[f][o] (r==20), as bf16 (col-major per output)
__global__ void wt_convert(const float* __restrict__ W1, const float* __restrict__ root1,
                           __hip_bfloat16* __restrict__ Wt) {
    int r = blockIdx.x;  // 0..20
    const float* src = (r < N_RELS) ? (W1 + (size_t)r * F_IN * HID) : root1;
    for (int i = threadIdx.x; i < F_IN * HID; i += 256) {
        int f = i >> 4, o = i & 15;
        Wt[((size_t)r * HID + o) * F_IN + f] = __float2bfloat16(src[i]);
    }
}

// h1[r][n][j] = sum_f x[n][f] * W_r[f][j] for r=0..20 (20 rels + root).
// One block = 64 nodes (4 waves x 16). x loaded ONCE, held as bf16 MFMA B-frags
// in registers; loop over 21 relations reusing the frags (W is L1/L2-resident).
// Operand swap: A = W^T (ocol-major), B = x^T -> lane holds 4 consecutive ocols
// for one node -> packed 8B bf16 stores.
__global__ __launch_bounds__(256) void xform_gemm(const float* __restrict__ x,
                                                  const __hip_bfloat16* __restrict__ Wt,
                                                  __hip_bfloat16* __restrict__ h1) {
    int wave = threadIdx.x >> 6;         // 0..3
    int lane = threadIdx.x & 63;
    int col = lane & 15;                 // node-within-tile (B col) / ocol (A row)
    int kgrp = lane >> 4;                // 0..3
    int node = blockIdx.x * 64 + wave * 16 + col;
    bool valid = node < N_NODES;

    // B-frags: x^T; lane supplies x[node][kgrp*8 + 32*s .. +8]
    bf16x8 xf[4];
    const float* xrow = x + (size_t)node * F_IN;
#pragma unroll
    for (int s = 0; s < 4; ++s) {
        int k0 = s * 32 + kgrp * 8;
        float4 a = valid ? *(const float4*)(xrow + k0)     : float4{0.f, 0.f, 0.f, 0.f};
        float4 b = valid ? *(const float4*)(xrow + k0 + 4) : float4{0.f, 0.f, 0.f, 0.f};
        bf16x8 v;
        v[0] = f2bf(a.x); v[1] = f2bf(a.y); v[2] = f2bf(a.z); v[3] = f2bf(a.w);
        v[4] = f2bf(b.x); v[5] = f2bf(b.y); v[6] = f2bf(b.z); v[7] = f2bf(b.w);
        xf[s] = v;
    }

    for (int r = 0; r < N_RELS + 1; ++r) {
        f32x4 acc = {0.f, 0.f, 0.f, 0.f};
        const __hip_bfloat16* wr = Wt + ((size_t)r * HID + col) * F_IN;  // A row = ocol
#pragma unroll
        for (int s = 0; s < 4; ++s) {
            bf16x8 wf = *(const bf16x8*)(wr + s * 32 + kgrp * 8);
            acc = __builtin_amdgcn_mfma_f32_16x16x32_bf16(wf, xf[s], acc, 0, 0, 0);
        }
        if (valid) {
            // lane holds D[ocol = kgrp*4+q][node]; store 4 bf16 = 8B
            union { ushort4 u4; short s4[4]; } o;
            o.s4[0] = f2bf(acc[0]); o.s4[1] = f2bf(acc[1]);
            o.s4[2] = f2bf(acc[2]); o.s4[3] = f2bf(acc[3]);
            *(ushort4*)(h1 + ((size_t)r * N_NODES + node) * HID + kgrp * 4) = o.u4;
        }
    }
}

// gather precomputed h1, scale by 1/cnt, scatter-add into agg1
__global__ void conv1_gather(const __hip_bfloat16* __restrict__ h1,
                             const int* __restrict__ src, const int* __restrict__ dst,
                             const int* __restrict__ et, const int* __restrict__ cnt,
                             float* __restrict__ agg1) {
    int g = (blockIdx.x * 256 + threadIdx.x) >> 4;  // edge id
    int lane = threadIdx.x & 15;
    if (g < N_EDGES) {
        int r = et[g], s = src[g], d = dst[g];
        float norm = 1.0f / (float)cnt[r * N_NODES + d];
        float v = __bfloat162float(h1[((size_t)(r * N_NODES + s)) * HID + lane]);
        atomicAdd(&agg1[d * HID + lane], v * norm);
    }
}

// out1 = agg1 + h1[root] + b1 (in place into agg1) + accumulate BN stats
__global__ void fuse1(float* __restrict__ agg1, const __hip_bfloat16* __restrict__ h1root,
                      const float* __restrict__ b1, float* __restrict__ st1) {
    __shared__ float ls[HID], lq[HID];
    if (threadIdx.x < HID) { ls[threadIdx.x] = 0.f; lq[threadIdx.x] = 0.f; }
    __syncthreads();
    int j = threadIdx.x & (HID - 1);
    float bj = b1[j];
    float s = 0.f, q = 0.f;
    for (int i = blockIdx.x * blockDim.x + threadIdx.x; i < N_NODES * HID;
         i += gridDim.x * blockDim.x) {
        float v = agg1[i] + __bfloat162float(h1root[i]) + bj;
        agg1[i] = v;
        s += v; q += v * v;
    }
    atomicAdd(&ls[j], s);
    atomicAdd(&lq[j], q);
    __syncthreads();
    if (threadIdx.x < HID) {
        atomicAdd(&st1[threadIdx.x], ls[threadIdx.x]);
        atomicAdd(&st1[HID + threadIdx.x], lq[threadIdx.x]);
    }
}

// BN + ReLU in place on agg1 (becomes hbn)
__global__ void bn_relu1(float* __restrict__ a, const float* __restrict__ stats,
                         const float* __restrict__ gamma, const float* __restrict__ beta) {
    int i = blockIdx.x * 256 + threadIdx.x;
    if (i < N_NODES * HID) {
        int j = i & (HID - 1);
        float mean = stats[j] * (1.0f / N_NODES);
        float var = stats[HID + j] * (1.0f / N_NODES) - mean * mean;
        float rs = rsqrtf(var + BN_EPS);
        float val = (a[i] - mean) * rs * gamma[j] + beta[j];
        a[i] = fmaxf(val, 0.f);
    }
}

__global__ void conv2_edge(const float* __restrict__ hbn, const float* __restrict__ W2,
                           const int* __restrict__ src, const int* __restrict__ dst,
                           const int* __restrict__ et, const int* __restrict__ cnt,
                           float* __restrict__ agg2) {
    __shared__ float w[N_RELS * HID * N_CLASSES];  // 40KB
    for (int i = threadIdx.x; i < N_RELS * HID * N_CLASSES; i += 256) w[i] = W2[i];
    __syncthreads();
    int grp = threadIdx.x >> 5, lane = threadIdx.x & 31;
    int base = blockIdx.x * 256;
    for (int it = 0; it < 32; ++it) {
        int e = base + it * 8 + grp;
        if (e < N_EDGES) {
            int r = et[e], s = src[e], d = dst[e];
            float norm = 1.0f / (float)cnt[r * N_NODES + d];
            const float4* hp = (const float4*)(hbn + (size_t)s * HID);
            const float* wr = w + r * (HID * N_CLASSES) + lane;
            float4 a0 = hp[0], a1 = hp[1], a2 = hp[2], a3 = hp[3];
            float acc = 0.f;
            acc = fmaf(a0.x, wr[0 * 32], acc);  acc = fmaf(a0.y, wr[1 * 32], acc);
            acc = fmaf(a0.z, wr[2 * 32], acc);  acc = fmaf(a0.w, wr[3 * 32], acc);
            acc = fmaf(a1.x, wr[4 * 32], acc);  acc = fmaf(a1.y, wr[5 * 32], acc);
            acc = fmaf(a1.z, wr[6 * 32], acc);  acc = fmaf(a1.w, wr[7 * 32], acc);
            acc = fmaf(a2.x, wr[8 * 32], acc);  acc = fmaf(a2.y, wr[9 * 32], acc);
            acc = fmaf(a2.z, wr[10 * 32], acc); acc = fmaf(a2.w, wr[11 * 32], acc);
            acc = fmaf(a3.x, wr[12 * 32], acc); acc = fmaf(a3.y, wr[13 * 32], acc);
            acc = fmaf(a3.z, wr[14 * 32], acc); acc = fmaf(a3.w, wr[15 * 32], acc);
            atomicAdd(&agg2[(size_t)d * N_CLASSES + lane], acc * norm);
        }
    }
}

__global__ void root2_kernel(const float* __restrict__ hbn, const float* __restrict__ root2,
                             const float* __restrict__ b2, float* __restrict__ buf2) {
    __shared__ float w[HID * N_CLASSES];
    for (int i = threadIdx.x; i < HID * N_CLASSES; i += 256) w[i] = root2[i];
    __syncthreads();
    int grp = threadIdx.x >> 5, lane = threadIdx.x & 31;
    int n = blockIdx.x * 8 + grp;
    if (n < N_NODES) {
        const float4* hp = (const float4*)(hbn + (size_t)n * HID);
        float4 a0 = hp[0], a1 = hp[1], a2 = hp[2], a3 = hp[3];
        float acc = 0.f;
        acc = fmaf(a0.x, w[0 * 32 + lane], acc);  acc = fmaf(a0.y, w[1 * 32 + lane], acc);
        acc = fmaf(a0.z, w[2 * 32 + lane], acc);  acc = fmaf(a0.w, w[3 * 32 + lane], acc);
        acc = fmaf(a1.x, w[4 * 32 + lane], acc);  acc = fmaf(a1.y, w[5 * 32 + lane], acc);
        acc = fmaf(a1.z, w[6 * 32 + lane], acc);  acc = fmaf(a1.w, w[7 * 32 + lane], acc);
        acc = fmaf(a2.x, w[8 * 32 + lane], acc);  acc = fmaf(a2.y, w[9 * 32 + lane], acc);
        acc = fmaf(a2.z, w[10 * 32 + lane], acc); acc = fmaf(a2.w, w[11 * 32 + lane], acc);
        acc = fmaf(a3.x, w[12 * 32 + lane], acc); acc = fmaf(a3.y, w[13 * 32 + lane], acc);
        acc = fmaf(a3.z, w[14 * 32 + lane], acc); acc = fmaf(a3.w, w[15 * 32 + lane], acc);
        size_t o = (size_t)n * N_CLASSES + lane;
        buf2[o] = buf2[o] + acc + b2[lane];
    }
}

template <int CH>
__global__ void bn_stats(const float* __restrict__ v, float* __restrict__ stats) {
    __shared__ float ls[CH], lq[CH];
    if (threadIdx.x < CH) { ls[threadIdx.x] = 0.f; lq[threadIdx.x] = 0.f; }
    __syncthreads();
    const int total = N_NODES * CH;
    int j = threadIdx.x % CH;
    float s = 0.f, q = 0.f;
    for (int i = blockIdx.x * blockDim.x + threadIdx.x; i < total; i += gridDim.x * blockDim.x) {
        float t = v[i];
        s += t; q += t * t;
    }
    atomicAdd(&ls[j], s);
    atomicAdd(&lq[j], q);
    __syncthreads();
    if (threadIdx.x < CH) {
        atomicAdd(&stats[threadIdx.x], ls[threadIdx.x]);
        atomicAdd(&stats[CH + threadIdx.x], lq[threadIdx.x]);
    }
}

__global__ void final_kernel(const float* __restrict__ buf2, const float* __restrict__ stats,
                             const float* __restrict__ gamma, const float* __restrict__ beta,
                             float* __restrict__ out) {
    int idx = blockIdx.x * 256 + threadIdx.x;  // over N*32, exact
    int j = threadIdx.x & 31;
    float mean = stats[j] * (1.0f / N_NODES);
    float var = stats[N_CLASSES + j] * (1.0f / N_NODES) - mean * mean;
    float rs = rsqrtf(var + BN_EPS);
    float v = fmaxf((buf2[idx] - mean) * rs * gamma[j] + beta[j], 0.f);
    float m = v;
#pragma unroll
    for (int o = 16; o >= 1; o >>= 1) m = fmaxf(m, __shfl_xor(m, o, 32));
    float ex = __expf(v - m);
    float ssum = ex;
#pragma unroll
    for (int o = 16; o >= 1; o >>= 1) ssum += __shfl_xor(ssum, o, 32);
    out[idx] = (v - m) - logf(ssum);
}

// ---------------- launcher ----------------
extern "C" void kernel_launch(void* const* d_in, const int* in_sizes, int n_in,
                              void* d_out, int out_size, void* d_ws, size_t ws_size,
                              hipStream_t stream) {
    const float* x      = (const float*)d_in[0];
    const int*   eidx   = (const int*)d_in[1];
    const int*   etype  = (const int*)d_in[2];
    const float* W1     = (const float*)d_in[3];
    const float* root1  = (const float*)d_in[4];
    const float* b1     = (const float*)d_in[5];
    const float* gamma1 = (const float*)d_in[6];
    const float* beta1  = (const float*)d_in[7];
    const float* W2     = (const float*)d_in[8];
    const float* root2  = (const float*)d_in[9];
    const float* b2     = (const float*)d_in[10];
    const float* gamma2 = (const float*)d_in[11];
    const float* beta2  = (const float*)d_in[12];

    const int* src = eidx;
    const int* dst = eidx + N_EDGES;

    char* ws = (char*)d_ws;
    int*   cnt  = (int*)(ws + OFF_CNT);
    float* agg1 = (float*)(ws + OFF_AGG1);   // also out1 / hbn, in place
    float* buf2 = (float*)(ws + OFF_BUF2);
    float* st1  = (float*)(ws + OFF_ST1);
    float* st2  = (float*)(ws + OFF_ST2);
    __hip_bfloat16* Wt = (__hip_bfloat16*)(ws + OFF_WT);
    __hip_bfloat16* h1 = (__hip_bfloat16*)(ws + OFF_H1);
    const __hip_bfloat16* h1root = h1 + (size_t)N_RELS * N_NODES * HID;

    float* out = (float*)d_out;

    hipMemsetAsync(cnt, 0, 8000000ull, stream);
    hipMemsetAsync(agg1, 0, 6400000ull, stream);
    hipMemsetAsync(buf2, 0, 12800000ull, stream);
    hipMemsetAsync(st1, 0, 256, stream);
    hipMemsetAsync(st2, 0, 256, stream);

    count_kernel<<<(N_EDGES + 255) / 256, 256, 0, stream>>>(etype, dst, cnt);
    wt_convert<<<N_RELS + 1, 256, 0, stream>>>(W1, root1, Wt);
    xform_gemm<<<(N_NODES + 63) / 64, 256, 0, stream>>>(x, Wt, h1);

    const int edge16_blocks = (N_EDGES * 16 + 255) / 256;  // 200000
    conv1_gather<<<edge16_blocks, 256, 0, stream>>>(h1, src, dst, etype, cnt, agg1);

    fuse1<<<512, 256, 0, stream>>>(agg1, h1root, b1, st1);
    bn_relu1<<<(N_NODES * HID + 255) / 256, 256, 0, stream>>>(agg1, st1, gamma1, beta1);

    conv2_edge<<<(N_EDGES + 255) / 256, 256, 0, stream>>>(agg1, W2, src, dst, etype, cnt, buf2);
    root2_kernel<<<(N_NODES + 7) / 8, 256, 0, stream>>>(agg1, root2, b2, buf2);
    bn_stats<N_CLASSES><<<512, 256, 0, stream>>>(buf2, st2);
    final_kernel<<<(N_NODES * N_CLASSES + 255) / 256, 256, 0, stream>>>(buf2, st2, gamma2, beta2, out);
}